// Round 7
// baseline (258.146 us; speedup 1.0000x reference)
//
#include <hip/hip_runtime.h>
#include <math.h>

constexpr int BLK = 256;
constexpr int NB_MAX = 256;      // max coarse buckets (supports N <= 131072)
constexpr int BSHIFT = 9;        // 512 nodes per bucket
constexpr int BSPAN = 1 << BSHIFT;
constexpr int CAP = 10240;       // per-bucket bin capacity (mean 8192 @ E=1.6M)
constexpr int EPT2 = 16;         // edges per thread in binpass
constexpr int EPBB = BLK * EPT2; // 4096 edges per block

typedef unsigned short u16;
typedef __attribute__((ext_vector_type(4))) unsigned short ushort4_t;

// ---- bf16 helpers (storage-only precision reduction for gather arrays) ----
__device__ __forceinline__ float bf2f(u16 u) {
  union { unsigned int i; float f; } v;
  v.i = ((unsigned int)u) << 16;
  return v.f;
}
__device__ __forceinline__ u16 f2bf(float f) {
  union { float f; unsigned int i; } v;
  v.f = f;
  unsigned int r = v.i + 0x7FFF + ((v.i >> 16) & 1);  // RNE
  return (u16)(r >> 16);
}

// ---------------- pass 1: coarse binning into block-private chunks ----------------
__global__ void __launch_bounds__(BLK) binpass(const int* __restrict__ src,
                                               const int* __restrict__ dst,
                                               int e, int* __restrict__ bins,
                                               int* __restrict__ tail) {
  __shared__ int lcnt[NB_MAX], gbase[NB_MAX], lcur[NB_MAX];
  const int tid = threadIdx.x;
  lcnt[tid] = 0;
  lcur[tid] = 0;
  __syncthreads();
  const int i0 = blockIdx.x * EPBB;
  int bb[EPT2], pk[EPT2];
#pragma unroll
  for (int k = 0; k < EPT2; k++) {
    int i = i0 + k * BLK + tid;
    if (i < e) {
      int d = dst[i], s = src[i];
      bb[k] = d >> BSHIFT;
      pk[k] = ((d & (BSPAN - 1)) << 23) | s;   // src < 2^23, dlo < 2^9
      atomicAdd(&lcnt[bb[k]], 1);
    } else {
      bb[k] = -1;
    }
  }
  __syncthreads();
  gbase[tid] = atomicAdd(&tail[tid], lcnt[tid]);  // reserve contiguous chunk per bucket
  __syncthreads();
#pragma unroll
  for (int k = 0; k < EPT2; k++) {
    if (bb[k] >= 0) {
      int idx = atomicAdd(&lcur[bb[k]], 1);
      bins[bb[k] * CAP + gbase[bb[k]] + idx] = pk[k];
    }
  }
}

// ---------------- pass 2: exclusive scan of bucket totals ----------------
__global__ void __launch_bounds__(BLK) scan256(const int* __restrict__ tail,
                                               int* __restrict__ bbase,
                                               int* __restrict__ row_ptr,
                                               int n, int e) {
  __shared__ int sd[BLK];
  int v = tail[threadIdx.x];
  sd[threadIdx.x] = v;
  __syncthreads();
  for (int off = 1; off < BLK; off <<= 1) {
    int t = (threadIdx.x >= off) ? sd[threadIdx.x - off] : 0;
    __syncthreads();
    sd[threadIdx.x] += t;
    __syncthreads();
  }
  bbase[threadIdx.x] = sd[threadIdx.x] - v;
  if (threadIdx.x == 0) row_ptr[n] = e;
}

// ---------------- pass 3: per-bucket counting sort (block-private col region) ----------------
__global__ void __launch_bounds__(BLK) bucket_sort(const int* __restrict__ bins,
                                                   const int* __restrict__ tail,
                                                   const int* __restrict__ bbase,
                                                   int* __restrict__ row_ptr,
                                                   int* __restrict__ col,
                                                   float* __restrict__ dinv, int n) {
  __shared__ int hist[BSPAN], lpre[BSPAN], lcur[BSPAN], sd[BLK];
  const int b = blockIdx.x, tid = threadIdx.x;
  const int cnt = tail[b];
  const int base = bbase[b];
  const int node0 = b << BSHIFT;
  const int nNodes = min(BSPAN, n - node0);
  const int* bin = bins + (size_t)b * CAP;

  hist[tid] = 0; hist[tid + BLK] = 0;
  lcur[tid] = 0; lcur[tid + BLK] = 0;
  __syncthreads();
  for (int j = tid; j < cnt; j += BLK) atomicAdd(&hist[(unsigned)bin[j] >> 23], 1);
  __syncthreads();
  // exclusive scan over 512 counters (2 per thread)
  int v0 = hist[2 * tid], v1 = hist[2 * tid + 1], ts = v0 + v1;
  sd[tid] = ts;
  __syncthreads();
  for (int off = 1; off < BLK; off <<= 1) {
    int t = (tid >= off) ? sd[tid - off] : 0;
    __syncthreads();
    sd[tid] += t;
    __syncthreads();
  }
  int ex = sd[tid] - ts;
  lpre[2 * tid] = ex;
  lpre[2 * tid + 1] = ex + v0;
  __syncthreads();
  for (int d = tid; d < nNodes; d += BLK) {
    row_ptr[node0 + d] = base + lpre[d];
    dinv[node0 + d] = rsqrtf((float)hist[d] + 1.0f);
  }
  for (int j = tid; j < cnt; j += BLK) {
    int pkv = bin[j];
    int dlo = (unsigned)pkv >> 23;
    int idx = atomicAdd(&lcur[dlo], 1);
    col[base + lpre[dlo] + idx] = pkv & 0x7FFFFF;
  }
}

// ---------------- dense GEMM: G[n][M] = bf16((X[n][K] @ W[K][M]) * dinv[n]) ----------------
// 256 threads = CGS col-groups x RGS row-groups; each thread R rows x C=4 cols.
// X staged in K-chunks, stride KSTAGE+4 (lane-major rows -> uniform bank coverage).
// W staged per chunk (row-major, uniform). 26KB LDS, ~4 waves/SIMD.
template <int K, int M, int R, int KSTAGE>
__global__ void __launch_bounds__(BLK) gemm_rt(const float* __restrict__ X,
                                               const float* __restrict__ W,
                                               const float* __restrict__ dinv,
                                               u16* __restrict__ G, int n) {
  constexpr int C = 4;
  constexpr int CGS = M / C;
  constexpr int RGS = BLK / CGS;
  constexpr int ROWS = RGS * R;
  __shared__ float xs[ROWS][KSTAGE + 4];
  __shared__ float ws[KSTAGE][M];
  const int tid = threadIdx.x;
  const int row0 = blockIdx.x * ROWS;
  const int cg = tid % CGS;
  const int rgl = tid / CGS;

  float acc[R][C];
#pragma unroll
  for (int r = 0; r < R; r++)
#pragma unroll
    for (int c = 0; c < C; c++) acc[r][c] = 0.f;

  constexpr int XIT = ROWS * (KSTAGE / 4) / BLK;
  constexpr int WIT = KSTAGE * (M / 4) / BLK;

  for (int ks = 0; ks < K; ks += KSTAGE) {
    __syncthreads();
#pragma unroll
    for (int jj = 0; jj < XIT; jj++) {
      int f = tid + BLK * jj;
      int r = f % ROWS, c4 = f / ROWS;
      int gr = row0 + r;
      if (gr >= n) gr = n - 1;  // clamp (stores guarded)
      *(float4*)&xs[r][c4 * 4] = *(const float4*)&X[(size_t)gr * K + ks + c4 * 4];
    }
#pragma unroll
    for (int jj = 0; jj < WIT; jj++) {
      int f = tid + BLK * jj;
      int k = f / (M / 4), c4 = f % (M / 4);
      *(float4*)&ws[k][c4 * 4] = *(const float4*)&W[(size_t)(ks + k) * M + c4 * 4];
    }
    __syncthreads();
#pragma unroll
    for (int k4 = 0; k4 < KSTAGE; k4 += 4) {
      float4 xa[R];
#pragma unroll
      for (int r = 0; r < R; r++) xa[r] = *(const float4*)&xs[rgl + RGS * r][k4];
      float4 w0 = *(const float4*)&ws[k4 + 0][cg * C];
      float4 w1 = *(const float4*)&ws[k4 + 1][cg * C];
      float4 w2 = *(const float4*)&ws[k4 + 2][cg * C];
      float4 w3 = *(const float4*)&ws[k4 + 3][cg * C];
#pragma unroll
      for (int r = 0; r < R; r++) {
        acc[r][0] += xa[r].x * w0.x + xa[r].y * w1.x + xa[r].z * w2.x + xa[r].w * w3.x;
        acc[r][1] += xa[r].x * w0.y + xa[r].y * w1.y + xa[r].z * w2.y + xa[r].w * w3.y;
        acc[r][2] += xa[r].x * w0.z + xa[r].y * w1.z + xa[r].z * w2.z + xa[r].w * w3.z;
        acc[r][3] += xa[r].x * w0.w + xa[r].y * w1.w + xa[r].z * w2.w + xa[r].w * w3.w;
      }
    }
  }

#pragma unroll
  for (int r = 0; r < R; r++) {
    int gr = row0 + rgl + RGS * r;
    if (gr < n) {
      float s = dinv[gr];
      u16 tmp[C];
#pragma unroll
      for (int c = 0; c < C; c++) tmp[c] = f2bf(acc[r][c] * s);
      *(ushort4_t*)&G[(size_t)gr * M + cg * C] = *(ushort4_t*)tmp;
    }
  }
}

// ---------------- aggregation ----------------
// gs (bf16) holds (X@W)*dinv[row]. out[i] = relu(dinv[i]*(gs[i] + sum_s gs[s]) + b)

__global__ void __launch_bounds__(BLK) agg1_kernel(const u16* __restrict__ gs,
                                                   const int* __restrict__ row_ptr,
                                                   const int* __restrict__ col,
                                                   const float* __restrict__ dinv,
                                                   const float* __restrict__ bias,
                                                   float* __restrict__ out, int n) {
  int node = (blockIdx.x * BLK + threadIdx.x) >> 6;
  int lane = threadIdx.x & 63;
  if (node >= n) return;
  int beg = row_ptr[node], end = row_ptr[node + 1];
  float acc = bf2f(gs[(size_t)node * 64 + lane]);  // self-loop (prescaled)
  int e1 = end - 1;
  for (int j = beg; j < end; j += 8) {
    int s[8];
#pragma unroll
    for (int t = 0; t < 8; t++) {
      int jj = j + t;
      s[t] = col[jj <= e1 ? jj : e1];
    }
    float a[8];
#pragma unroll
    for (int t = 0; t < 8; t++) a[t] = bf2f(gs[(size_t)s[t] * 64 + lane]);
#pragma unroll
    for (int t = 0; t < 8; t++) acc += (j + t <= e1) ? a[t] : 0.f;
  }
  float v = acc * dinv[node] + bias[lane];
  out[(size_t)node * 64 + lane] = v > 0.f ? v : 0.f;
}

__global__ void __launch_bounds__(BLK) agg2_kernel(const u16* __restrict__ gs,
                                                   const int* __restrict__ row_ptr,
                                                   const int* __restrict__ col,
                                                   const float* __restrict__ dinv,
                                                   const float* __restrict__ bias,
                                                   float* __restrict__ out, int n) {
  int node = (blockIdx.x * BLK + threadIdx.x) >> 6;
  int lane = threadIdx.x & 63;
  if (node >= n) return;
  int c = lane & 31, half = lane >> 5;
  float acc = (half == 0) ? bf2f(gs[(size_t)node * 32 + c]) : 0.f;
  int beg = row_ptr[node], end = row_ptr[node + 1];
  int e1 = end - 1;
  for (int j = beg + half; j < end; j += 8) {
    int s[4];
#pragma unroll
    for (int t = 0; t < 4; t++) {
      int jj = j + 2 * t;
      s[t] = col[jj <= e1 ? jj : e1];
    }
    float a[4];
#pragma unroll
    for (int t = 0; t < 4; t++) a[t] = bf2f(gs[(size_t)s[t] * 32 + c]);
#pragma unroll
    for (int t = 0; t < 4; t++) acc += (j + 2 * t <= e1) ? a[t] : 0.f;
  }
  acc += __shfl_xor(acc, 32);
  if (half == 0) {
    float v = acc * dinv[node] + bias[c];
    out[(size_t)node * 32 + c] = v > 0.f ? v : 0.f;
  }
}

// ---------------- launcher ----------------

extern "C" void kernel_launch(void* const* d_in, const int* in_sizes, int n_in,
                              void* d_out, int out_size, void* d_ws, size_t ws_size,
                              hipStream_t stream) {
  const float* x = (const float*)d_in[0];
  const int* ei = (const int*)d_in[1];
  const float* W1 = (const float*)d_in[2];
  const float* b1 = (const float*)d_in[3];
  const float* W2 = (const float*)d_in[4];
  const float* b2 = (const float*)d_in[5];

  const int N = in_sizes[0] / 128;
  const int E = in_sizes[1] / 2;
  const int* src = ei;
  const int* dst = ei + E;
  const int nb = (N + BSPAN - 1) >> BSHIFT;  // # coarse buckets (196 @ N=100K)

  char* p = (char*)d_ws;
  auto take = [&](size_t bytes) -> char* {
    char* q = p;
    p += (bytes + 255) & ~(size_t)255;
    return q;
  };
  int* bins = (int*)take((size_t)NB_MAX * CAP * 4);
  int* tail = (int*)take(NB_MAX * 4);
  int* bbase = (int*)take(NB_MAX * 4);
  int* row_ptr = (int*)take((size_t)(N + 1) * 4);
  int* col = (int*)take((size_t)E * 4);
  float* dinv = (float*)take((size_t)N * 4);
  u16* g1 = (u16*)take((size_t)N * 64 * 2);
  float* h = (float*)take((size_t)N * 64 * 4);
  u16* g2 = (u16*)take((size_t)N * 32 * 2);

  hipMemsetAsync(tail, 0, NB_MAX * 4, stream);

  binpass<<<(E + EPBB - 1) / EPBB, BLK, 0, stream>>>(src, dst, E, bins, tail);
  scan256<<<1, BLK, 0, stream>>>(tail, bbase, row_ptr, N, E);
  bucket_sort<<<nb, BLK, 0, stream>>>(bins, tail, bbase, row_ptr, col, dinv, N);

  gemm_rt<128, 64, 8, 32><<<(N + 127) / 128, BLK, 0, stream>>>(x, W1, dinv, g1, N);
  agg1_kernel<<<(N + 3) / 4, BLK, 0, stream>>>(g1, row_ptr, col, dinv, b1, h, N);
  gemm_rt<64, 32, 4, 32><<<(N + 127) / 128, BLK, 0, stream>>>(h, W2, dinv, g2, N);
  agg2_kernel<<<(N + 3) / 4, BLK, 0, stream>>>(g2, row_ptr, col, dinv, b2, (float*)d_out, N);
}